// Round 14
// baseline (258.421 us; speedup 1.0000x reference)
//
#include <hip/hip_runtime.h>

#define N_NODES 100000
#define IN_CH 128
#define HID 75
#define OUT_CH 40
#define N_EDGES 3200000

#define NB 196          // buckets of 512 dst nodes
#define CAP 20000       // per-bucket capacity; mean 16384
#define EPT 16          // edges per thread in passA
#define PA_EDGES (EPT * 256)

typedef unsigned short u16;
typedef unsigned int u32;
typedef unsigned char u8;
typedef short short8 __attribute__((ext_vector_type(8)));
typedef float f32x4 __attribute__((ext_vector_type(4)));
typedef float f32x2 __attribute__((ext_vector_type(2)));
typedef u32 u32x2 __attribute__((ext_vector_type(2)));
typedef u32 u32x4 __attribute__((ext_vector_type(4)));
typedef u32x4 u32x4u __attribute__((aligned(4)));   // 4B-aligned dwordx4 load

__device__ __forceinline__ u16 f2bf(float f) {
    u32 b = __float_as_uint(f);
    b += 0x7FFF + ((b >> 16) & 1);   // round-to-nearest-even
    return (u16)(b >> 16);
}

#if __has_builtin(__builtin_amdgcn_cvt_pk_f32_fp8) && __has_builtin(__builtin_amdgcn_cvt_pk_fp8_f32)
#define HW_FP8 1
#else
#define HW_FP8 0
#endif

// ---- fp8 e4m3 decode: 2 values from the low/high word of a u32 -----------
__device__ __forceinline__ float dec1_sw(u32 v) {
    u32 s = (v & 0x80u) << 24;
    u32 em = v & 0x7Fu;
    float mag = (em >= 8u) ? __uint_as_float((em << 20) + (120u << 23))
                           : (float)em * 0.001953125f;   // denormal: m * 2^-9
    return __uint_as_float(s | __float_as_uint(mag));
}
template <int HI>
__device__ __forceinline__ f32x2 dec2(u32 w) {
#if HW_FP8
    return __builtin_amdgcn_cvt_pk_f32_fp8(w, HI);
#else
    f32x2 r;
    r.x = dec1_sw((w >> (HI * 16)) & 0xFFu);
    r.y = dec1_sw((w >> (HI * 16 + 8)) & 0xFFu);
    return r;
#endif
}
// ---- fp8 e4m3 encode (RNE, clamp to +-448) -------------------------------
__device__ __forceinline__ u32 enc1(float f) {
#if HW_FP8
    return __builtin_amdgcn_cvt_pk_fp8_f32(f, f, 0u, false) & 0xFFu;
#else
    float cf = fminf(fmaxf(f, -448.f), 448.f);
    u32 b = __float_as_uint(cf);
    u32 sign = (b >> 24) & 0x80u;
    float af = fabsf(cf);
    if (af < 0.015625f) {                       // denormal range, step 2^-9
        u32 d = (u32)__builtin_rintf(af * 512.f);
        return sign | d;
    }
    u32 e = (b >> 23) & 0xFFu;
    u32 m = b & 0x7FFFFFu;
    u32 m8 = m >> 20;
    u32 rem = m & 0xFFFFFu;
    m8 += (rem > 0x80000u) || (rem == 0x80000u && (m8 & 1u));
    u32 ee = e - 120u;
    if (m8 == 8u) { m8 = 0u; ee += 1u; }
    if (ee > 15u || (ee == 15u && m8 == 7u)) { ee = 15u; m8 = 6u; }  // 448
    return sign | (ee << 3) | m8;
#endif
}

// ---------------- edge-index layout probe (int32 vs int64) ----------------
__global__ void probe64(const int* __restrict__ e, int* __restrict__ flag) {
    __shared__ int nonzero;
    if (threadIdx.x == 0) nonzero = 0;
    __syncthreads();
    int idx = threadIdx.x * 12497;              // < 3.2M
    if (e[2 * idx + 1] != 0) nonzero = 1;       // safe for both layouts
    __syncthreads();
    if (threadIdx.x == 0) *flag = (nonzero == 0) ? 1 : 0;
}

// zero bucket cursors, degree histogram, h1b K-pad (u32 cols 40..47)
__global__ __launch_bounds__(256) void init_misc(int* __restrict__ bucketCursor,
        int* __restrict__ degHist, u32* __restrict__ h1b32) {
    int i = blockIdx.x * 256 + threadIdx.x;
    if (i < NB * 16) bucketCursor[i] = 0;
    if (i < 256) degHist[i] = 0;
    if (i < 800000) {
        int node = i >> 3, q = i & 7;
        h1b32[node * 48 + 40 + q] = 0;
    }
}

// ---------------- pass A: bin edges into 196 dst-range buckets ------------
__global__ __launch_bounds__(256) void passA(const int* __restrict__ e,
        const int* __restrict__ flag, int* __restrict__ bucketCursor,
        unsigned* __restrict__ bucketBuf) {
    __shared__ int cnt[NB];
    __shared__ int base[NB];
    int t = threadIdx.x;
    for (int i = t; i < NB; i += 256) cnt[i] = 0;
    __syncthreads();
    bool w64 = (*flag != 0);
    int s_[EPT], d_[EPT];
    int eb = blockIdx.x * PA_EDGES + t;
#pragma unroll
    for (int k = 0; k < EPT; ++k) {
        int idx = eb + k * 256;
        int s = 0, d = -1;
        if (idx < N_EDGES) {
            if (w64) { s = e[2 * idx]; d = e[2 * (N_EDGES + idx)]; }
            else     { s = e[idx];     d = e[N_EDGES + idx]; }
            atomicAdd(&cnt[d >> 9], 1);
        }
        s_[k] = s; d_[k] = d;
    }
    __syncthreads();
    for (int i = t; i < NB; i += 256) {
        int c = cnt[i];
        base[i] = (c > 0) ? atomicAdd(&bucketCursor[i * 16], c) : 0;  // 64B-padded cursors
        cnt[i] = 0;
    }
    __syncthreads();
#pragma unroll
    for (int k = 0; k < EPT; ++k) {
        int d = d_[k];
        if (d >= 0) {
            int b = d >> 9;
            int off = atomicAdd(&cnt[b], 1);
            int pos = base[b] + off;
            if (pos < CAP)
                bucketBuf[(size_t)b * CAP + pos] =
                    ((unsigned)(d & 511) << 17) | (unsigned)s_[k];
        }
    }
}

// ---------------- scan of 196 bucket sizes -> bucket starts ---------------
__global__ __launch_bounds__(256) void scan196(const int* __restrict__ bucketCursor,
        int* __restrict__ bucketStart, int* __restrict__ rowStart) {
    __shared__ int a[256], b[256];
    int t = threadIdx.x;
    int v = (t < NB) ? bucketCursor[t * 16] : 0;
    a[t] = v;
    __syncthreads();
    int* pin = a; int* pout = b;
    for (int o = 1; o < 256; o <<= 1) {
        int nv = pin[t] + ((t >= o) ? pin[t - o] : 0);
        pout[t] = nv;
        __syncthreads();
        int* tmp = pin; pin = pout; pout = tmp;
    }
    if (t < NB) bucketStart[t] = pin[t] - v;  // exclusive
    if (t == 0) rowStart[N_NODES] = N_EDGES;
}

// ---------------- pass B: per-bucket CSR fill, all atomics in LDS ---------
__global__ __launch_bounds__(1024) void passB(const unsigned* __restrict__ bucketBuf,
        const int* __restrict__ bucketCursor, const int* __restrict__ bucketStart,
        int* __restrict__ csrSrc, int* __restrict__ rowStart, float* __restrict__ dinv) {
    __shared__ int cnt[512];
    __shared__ int sa[512], sb[512];
    int b = blockIdx.x;
    int t = threadIdx.x;
    int n = bucketCursor[b * 16];
    int start = bucketStart[b];
    if (t < 512) cnt[t] = 0;
    __syncthreads();
    const unsigned* buf = bucketBuf + (size_t)b * CAP;
    for (int i = t; i < n; i += 1024) atomicAdd(&cnt[buf[i] >> 17], 1);
    __syncthreads();
    if (t < 512) sa[t] = cnt[t];
    __syncthreads();
    int* pin = sa; int* pout = sb;
    for (int o = 1; o < 512; o <<= 1) {
        if (t < 512) pout[t] = pin[t] + ((t >= o) ? pin[t - o] : 0);
        __syncthreads();
        int* tmp = pin; pin = pout; pout = tmp;
    }
    int excl = 0;
    if (t < 512) {
        int deg = cnt[t];
        excl = pin[t] - deg;
        int node = b * 512 + t;
        if (node < N_NODES) {
            rowStart[node] = start + excl;
            dinv[node] = rsqrtf((float)deg + 1.0f);  // +1 self-loop
        }
    }
    __syncthreads();
    if (t < 512) cnt[t] = excl;   // LDS cursors
    __syncthreads();
    for (int i = t; i < n; i += 1024) {
        unsigned p = buf[i];
        int pos = atomicAdd(&cnt[p >> 17], 1);
        csrSrc[start + pos] = (int)(p & 0x1FFFF);
    }
}

// ---------------- degree-sorted node permutation (two-level LDS sort) -----
__global__ __launch_bounds__(1024) void hist_deg(const int* __restrict__ rowStart,
        int* __restrict__ degHist) {
    __shared__ int lh[256];
    int t = threadIdx.x;
    if (t < 256) lh[t] = 0;
    __syncthreads();
    int i = blockIdx.x * 1024 + t;
    if (i < N_NODES) {
        int deg = min(rowStart[i + 1] - rowStart[i], 255);
        atomicAdd(&lh[deg], 1);
    }
    __syncthreads();
    if (t < 256 && lh[t] > 0) atomicAdd(&degHist[t], lh[t]);
}
__global__ __launch_bounds__(256) void scan_bins(const int* __restrict__ degHist,
        int* __restrict__ binCursor) {
    __shared__ int a[256], b[256];
    int t = threadIdx.x;
    int v = degHist[t];
    a[t] = v;
    __syncthreads();
    int* pin = a; int* pout = b;
    for (int o = 1; o < 256; o <<= 1) {
        pout[t] = pin[t] + ((t >= o) ? pin[t - o] : 0);
        __syncthreads();
        int* tmp = pin; pin = pout; pout = tmp;
    }
    binCursor[t] = pin[t] - v;   // exclusive
}
__global__ __launch_bounds__(1024) void scatter_perm(const int* __restrict__ rowStart,
        int* __restrict__ binCursor, int* __restrict__ perm) {
    __shared__ int lh[256];
    __shared__ int lbase[256];
    int t = threadIdx.x;
    if (t < 256) lh[t] = 0;
    __syncthreads();
    int i = blockIdx.x * 1024 + t;
    int deg = 0, lo = 0;
    bool valid = (i < N_NODES);
    if (valid) {
        deg = min(rowStart[i + 1] - rowStart[i], 255);
        lo = atomicAdd(&lh[deg], 1);          // local offset (LDS, fast)
    }
    __syncthreads();
    if (t < 256) {
        int c = lh[t];
        lbase[t] = (c > 0) ? atomicAdd(&binCursor[t], c) : 0;
    }
    __syncthreads();
    if (valid) perm[lbase[deg] + lo] = i;
    else if (i < 100032) perm[i] = N_NODES;   // sentinel pad
}

// ---------------- prep: bf16 transposed weights ---------------------------
__global__ __launch_bounds__(256) void prep_w(const float* __restrict__ W1,
        const float* __restrict__ W2, u16* __restrict__ w1t, u16* __restrict__ w2t) {
    int g = blockIdx.x * 256 + threadIdx.x;
    int stride = gridDim.x * 256;
    for (int i = g; i < 80 * 128; i += stride) {
        int c = i >> 7, k = i & 127;
        w1t[i] = (c < HID) ? f2bf(W1[k * HID + c]) : (u16)0;
    }
    for (int i = g; i < 48 * 96; i += stride) {
        int c = i / 96, k = i - c * 96;
        w2t[i] = (c < OUT_CH && k < HID) ? f2bf(W2[k * OUT_CH + c]) : (u16)0;
    }
}

// ---------------- GEMM1 via MFMA -> 3 fp8 chunk tables (SCALE=8) ----------
// hsC0[node][32] feats 0..31, hsC1[node][32] feats 32..63, hsC2[node][16]
// feats 64..79 (75..79 zero via w1t padding). Each chunk table <= 3.2MB.
__global__ __launch_bounds__(256) void gemm1_mfma(const float* __restrict__ x,
        const u16* __restrict__ w1t, const float* __restrict__ dinv,
        u8* __restrict__ hsC0, u8* __restrict__ hsC1, u8* __restrict__ hsC2) {
    __shared__ u16 Wl[80 * 136];   // pad 128->136 elems: bank-spread rows
    int t = threadIdx.x;
    {
        const u32* ws = (const u32*)w1t;
        u32* wd = (u32*)Wl;
        for (int i = t; i < 80 * 64; i += 256) {
            int r = i >> 6, c = i & 63;
            wd[r * 68 + c] = ws[i];
        }
    }
    __syncthreads();
    int wid = t >> 6, lane = t & 63;
    int bl = lane & 15, kh = lane >> 4;
    int row0 = blockIdx.x * 64 + wid * 16;
    short8 bf[5][4];
#pragma unroll
    for (int ct = 0; ct < 5; ++ct)
#pragma unroll
        for (int ks = 0; ks < 4; ++ks)
            bf[ct][ks] = *(const short8*)&Wl[(ct * 16 + bl) * 136 + ks * 32 + kh * 8];
    f32x4 zero = {0.f, 0.f, 0.f, 0.f};
    f32x4 acc[5];
#pragma unroll
    for (int ct = 0; ct < 5; ++ct) acc[ct] = zero;
    int arow = row0 + bl;
    bool av = (arow < N_NODES);
    const float* xr = x + (size_t)arow * IN_CH + kh * 8;
#pragma unroll
    for (int ks = 0; ks < 4; ++ks) {
        short8 af = {0, 0, 0, 0, 0, 0, 0, 0};
        if (av) {
            float4 lo = *(const float4*)(xr + ks * 32);
            float4 hi = *(const float4*)(xr + ks * 32 + 4);
            af[0] = (short)f2bf(lo.x); af[1] = (short)f2bf(lo.y);
            af[2] = (short)f2bf(lo.z); af[3] = (short)f2bf(lo.w);
            af[4] = (short)f2bf(hi.x); af[5] = (short)f2bf(hi.y);
            af[6] = (short)f2bf(hi.z); af[7] = (short)f2bf(hi.w);
        }
#pragma unroll
        for (int ct = 0; ct < 5; ++ct)
            acc[ct] = __builtin_amdgcn_mfma_f32_16x16x32_bf16(af, bf[ct][ks], acc[ct], 0, 0, 0);
    }
    // C/D: col = lane&15, row = (lane>>4)*4 + reg  [HW-verified]
    int orow = row0 + kh * 4;
    float dn[4];
#pragma unroll
    for (int i = 0; i < 4; ++i)
        dn[i] = (orow + i < N_NODES) ? dinv[orow + i] * 8.f : 0.f;   // SCALE=8
#pragma unroll
    for (int ct = 0; ct < 5; ++ct) {
        int col = ct * 16 + bl;
#pragma unroll
        for (int i = 0; i < 4; ++i) {
            int r = orow + i;
            if (r < N_NODES) {
                u8 q8 = (u8)enc1(acc[ct][i] * dn[i]);
                if (ct < 2)      hsC0[(size_t)r * 32 + col] = q8;
                else if (ct < 4) hsC1[(size_t)r * 32 + (col - 32)] = q8;
                else             hsC2[(size_t)r * 16 + (col - 64)] = q8;
            }
        }
    }
}

// ---------------- GEMM2 via MFMA -> single padded fp8 table (SCALE=8) -----
// hs2P[node][64 u8]: feats 0..39 in bytes 0..39, bytes 40..63 unused pad
__global__ __launch_bounds__(256) void gemm2_mfma(const u16* __restrict__ h1b,
        const u16* __restrict__ w2t, const float* __restrict__ dinv,
        u8* __restrict__ hs2P) {
    __shared__ u16 Wl[48 * 104];   // pad 96->104
    int t = threadIdx.x;
    {
        const u32* ws = (const u32*)w2t;
        u32* wd = (u32*)Wl;
        for (int i = t; i < 48 * 48; i += 256) {
            int r = i / 48, c = i - r * 48;
            wd[r * 52 + c] = ws[i];
        }
    }
    __syncthreads();
    int wid = t >> 6, lane = t & 63;
    int bl = lane & 15, kh = lane >> 4;
    int row0 = blockIdx.x * 64 + wid * 16;
    short8 bf[3][3];
#pragma unroll
    for (int ct = 0; ct < 3; ++ct)
#pragma unroll
        for (int ks = 0; ks < 3; ++ks)
            bf[ct][ks] = *(const short8*)&Wl[(ct * 16 + bl) * 104 + ks * 32 + kh * 8];
    f32x4 zero = {0.f, 0.f, 0.f, 0.f};
    f32x4 acc[3];
#pragma unroll
    for (int ct = 0; ct < 3; ++ct) acc[ct] = zero;
    int arow = row0 + bl;
    bool av = (arow < N_NODES);
    const u16* hr = h1b + (size_t)arow * 96 + kh * 8;
#pragma unroll
    for (int ks = 0; ks < 3; ++ks) {
        short8 af = {0, 0, 0, 0, 0, 0, 0, 0};
        if (av) af = *(const short8*)(hr + ks * 32);
#pragma unroll
        for (int ct = 0; ct < 3; ++ct)
            acc[ct] = __builtin_amdgcn_mfma_f32_16x16x32_bf16(af, bf[ct][ks], acc[ct], 0, 0, 0);
    }
    int orow = row0 + kh * 4;
    float dn[4];
#pragma unroll
    for (int i = 0; i < 4; ++i)
        dn[i] = (orow + i < N_NODES) ? dinv[orow + i] * 8.f : 0.f;   // SCALE=8
#pragma unroll
    for (int ct = 0; ct < 3; ++ct) {
        int col = ct * 16 + bl;
#pragma unroll
        for (int i = 0; i < 4; ++i) {
            int r = orow + i;
            if (r < N_NODES && (ct < 2 || bl < 8)) {   // cols 0..39 only
                u8 q8 = (u8)enc1(acc[ct][i] * dn[i]);
                hs2P[(size_t)r * 64 + col] = q8;
            }
        }
    }
}

// ---------------- agg1 chunk kernel: 32B rows, L2-resident table ----------
// 8 groups x 8 lanes per wave; group owns one degree-sorted node; lane ll
// reads u32 (4 fp8 feats) at byte 4*ll of the 32B row. 1 line-request/edge.
__global__ __launch_bounds__(256) void agg1_c32(
        const u8* __restrict__ tab, const int* __restrict__ rowStart,
        const int* __restrict__ csrSrc, const int* __restrict__ perm,
        const float* __restrict__ dinv, const float* __restrict__ bias,
        u32* __restrict__ out, int fbase) {
    int wid = threadIdx.x >> 6, lane = threadIdx.x & 63;
    int g = lane >> 3, ll = lane & 7;
    int slot = (blockIdx.x * 4 + wid) * 8 + g;      // < 100032
    int node = perm[slot];
    bool valid = (node < N_NODES);
    int vnode = valid ? node : 0;
    int rs = rowStart[vnode];
    int end = valid ? rowStart[vnode + 1] : rs;
    u32 loff = (u32)ll * 4;
    f32x2 aLo = {0.f, 0.f}, aHi = {0.f, 0.f};
    if (valid) {                                    // self-loop
        u32 v = *(const u32*)(tab + (((u32)vnode << 5) + loff));
        aLo += dec2<0>(v); aHi += dec2<1>(v);
    }
    int j = rs;
    for (; j + 4 <= end; j += 4) {
        u32x4 i4 = *(const u32x4u*)(csrSrc + j);    // same addr across group
#pragma unroll
        for (int q = 0; q < 4; ++q) {
            u32 v = *(const u32*)(tab + ((i4[q] << 5) + loff));
            aLo += dec2<0>(v); aHi += dec2<1>(v);
        }
    }
    for (; j < end; ++j) {
        u32 v = *(const u32*)(tab + (((u32)csrSrc[j] << 5) + loff));
        aLo += dec2<0>(v); aHi += dec2<1>(v);
    }
    if (valid) {
        float dns = dinv[vnode] * 0.125f;           // undo SCALE=8
        int f0 = fbase + 4 * ll;
        float r0 = (f0     < HID) ? fmaxf(fmaf(dns, aLo.x, bias[f0]),     0.f) : 0.f;
        float r1 = (f0 + 1 < HID) ? fmaxf(fmaf(dns, aLo.y, bias[f0 + 1]), 0.f) : 0.f;
        float r2 = (f0 + 2 < HID) ? fmaxf(fmaf(dns, aHi.x, bias[f0 + 2]), 0.f) : 0.f;
        float r3 = (f0 + 3 < HID) ? fmaxf(fmaf(dns, aHi.y, bias[f0 + 3]), 0.f) : 0.f;
        u32x2 ov = { ((u32)f2bf(r1) << 16) | (u32)f2bf(r0),
                     ((u32)f2bf(r3) << 16) | (u32)f2bf(r2) };
        *(u32x2*)(out + (size_t)vnode * 48 + (fbase >> 1) + 2 * ll) = ov;
    }
}

// ---------------- agg1 chunk kernel: 16B rows (feats 64..79) --------------
// 16 groups x 4 lanes per wave.
__global__ __launch_bounds__(256) void agg1_c16(
        const u8* __restrict__ tab, const int* __restrict__ rowStart,
        const int* __restrict__ csrSrc, const int* __restrict__ perm,
        const float* __restrict__ dinv, const float* __restrict__ bias,
        u32* __restrict__ out) {
    int wid = threadIdx.x >> 6, lane = threadIdx.x & 63;
    int g = lane >> 2, ll = lane & 3;
    int slot = (blockIdx.x * 4 + wid) * 16 + g;     // < 100032
    int node = perm[slot];
    bool valid = (node < N_NODES);
    int vnode = valid ? node : 0;
    int rs = rowStart[vnode];
    int end = valid ? rowStart[vnode + 1] : rs;
    u32 loff = (u32)ll * 4;
    f32x2 aLo = {0.f, 0.f}, aHi = {0.f, 0.f};
    if (valid) {                                    // self-loop
        u32 v = *(const u32*)(tab + (((u32)vnode << 4) + loff));
        aLo += dec2<0>(v); aHi += dec2<1>(v);
    }
    int j = rs;
    for (; j + 4 <= end; j += 4) {
        u32x4 i4 = *(const u32x4u*)(csrSrc + j);
#pragma unroll
        for (int q = 0; q < 4; ++q) {
            u32 v = *(const u32*)(tab + ((i4[q] << 4) + loff));
            aLo += dec2<0>(v); aHi += dec2<1>(v);
        }
    }
    for (; j < end; ++j) {
        u32 v = *(const u32*)(tab + (((u32)csrSrc[j] << 4) + loff));
        aLo += dec2<0>(v); aHi += dec2<1>(v);
    }
    if (valid) {
        float dns = dinv[vnode] * 0.125f;           // undo SCALE=8
        int f0 = 64 + 4 * ll;
        float r0 = (f0     < HID) ? fmaxf(fmaf(dns, aLo.x, bias[f0]),     0.f) : 0.f;
        float r1 = (f0 + 1 < HID) ? fmaxf(fmaf(dns, aLo.y, bias[f0 + 1]), 0.f) : 0.f;
        float r2 = (f0 + 2 < HID) ? fmaxf(fmaf(dns, aHi.x, bias[f0 + 2]), 0.f) : 0.f;
        float r3 = (f0 + 3 < HID) ? fmaxf(fmaf(dns, aHi.y, bias[f0 + 3]), 0.f) : 0.f;
        u32x2 ov = { ((u32)f2bf(r1) << 16) | (u32)f2bf(r0),
                     ((u32)f2bf(r3) << 16) | (u32)f2bf(r2) };
        *(u32x2*)(out + (size_t)vnode * 48 + 32 + 2 * ll) = ov;
    }
}

// ---------------- aggregation layer 2: 8x8 groups + log_softmax -----------
__global__ __launch_bounds__(256) void aggregate2(
        const char* __restrict__ tab,
        const int* __restrict__ rowStart, const int* __restrict__ csrSrc,
        const int* __restrict__ perm, const float* __restrict__ dinv,
        const float* __restrict__ bias, float* __restrict__ out) {
    int wid = threadIdx.x >> 6, lane = threadIdx.x & 63;
    int g = lane >> 3, ll = lane & 7;
    int slot = (blockIdx.x * 4 + wid) * 8 + g;      // grid exact: < 100000
    int node = perm[slot];
    int rs = rowStart[node];
    int end = rowStart[node + 1];
    u32 loff = (u32)ll * 8;
    f32x2 a0 = {0.f, 0.f}, a1 = {0.f, 0.f}, a2 = {0.f, 0.f}, a3 = {0.f, 0.f};
    {                                   // self-loop
        u32x2 v = *(const u32x2*)(tab + (((u32)node << 6) + loff));
        a0 += dec2<0>(v.x); a1 += dec2<1>(v.x);
        a2 += dec2<0>(v.y); a3 += dec2<1>(v.y);
    }
    int j = rs;
    for (; j + 4 <= end; j += 4) {
        u32x4 i4 = *(const u32x4u*)(csrSrc + j);
#pragma unroll
        for (int q = 0; q < 4; ++q) {
            u32x2 v = *(const u32x2*)(tab + ((i4[q] << 6) + loff));
            a0 += dec2<0>(v.x); a1 += dec2<1>(v.x);
            a2 += dec2<0>(v.y); a3 += dec2<1>(v.y);
        }
    }
    for (; j < end; ++j) {
        u32 idx = (u32)csrSrc[j];
        u32x2 v = *(const u32x2*)(tab + ((idx << 6) + loff));
        a0 += dec2<0>(v.x); a1 += dec2<1>(v.x);
        a2 += dec2<0>(v.y); a3 += dec2<1>(v.y);
    }
    float tt[8] = {a0.x, a0.y, a1.x, a1.y, a2.x, a2.y, a3.x, a3.y};
    bool act5 = (ll < 5);
    float vk[8];
    float m = -3.4e38f;
    if (act5) {
        float dns = dinv[node] * 0.125f;   // undo SCALE=8
#pragma unroll
        for (int k = 0; k < 8; ++k) {
            vk[k] = fmaf(dns, tt[k], bias[8 * ll + k]);
            m = fmaxf(m, vk[k]);
        }
    }
#pragma unroll
    for (int o = 1; o < 8; o <<= 1) m = fmaxf(m, __shfl_xor(m, o));
    float e = 0.f;
    if (act5) {
#pragma unroll
        for (int k = 0; k < 8; ++k) e += expf(vk[k] - m);
    }
#pragma unroll
    for (int o = 1; o < 8; o <<= 1) e += __shfl_xor(e, o);
    float lse = logf(e);
    if (act5) {
        float4 r0 = make_float4(vk[0] - m - lse, vk[1] - m - lse,
                                vk[2] - m - lse, vk[3] - m - lse);
        float4 r1 = make_float4(vk[4] - m - lse, vk[5] - m - lse,
                                vk[6] - m - lse, vk[7] - m - lse);
        *(float4*)(out + (size_t)node * OUT_CH + 8 * ll) = r0;
        *(float4*)(out + (size_t)node * OUT_CH + 8 * ll + 4) = r1;
    }
}

extern "C" void kernel_launch(void* const* d_in, const int* in_sizes, int n_in,
                              void* d_out, int out_size, void* d_ws, size_t ws_size,
                              hipStream_t stream) {
    const float* x  = (const float*)d_in[0];
    const int*   e  = (const int*)d_in[1];
    const float* W1 = (const float*)d_in[2];
    const float* b1 = (const float*)d_in[3];
    const float* W2 = (const float*)d_in[4];
    const float* b2 = (const float*)d_in[5];
    float* out = (float*)d_out;

    // workspace carve (all sizes multiples of 16 B); total ~57 MB
    char* w = (char*)d_ws;
    u8* hsC0 = (u8*)w;                                   // 3.20 MB (aliases bucketBuf)
    u8* hsC1 = (u8*)(w + 3201024);                       // 3.20 MB (aliases bucketBuf)
    u8* hsC2 = (u8*)(w + 6402048);                       // 1.60 MB (aliases bucketBuf)
    unsigned* bucketBuf = (unsigned*)w;                  // 15.68 MB, dead after passB
    w += 15680000;
    u16* h1b  = (u16*)w; w += (size_t)100032 * 96 * 2;   // 19.2 MB
    int* csrSrc = (int*)w; w += (size_t)N_EDGES * 4;     // 12.8 MB
    u8* hs2P = (u8*)w; w += (size_t)100032 * 64;         // 6.40 MB
    int* rowStart = (int*)w; w += 400016;
    float* dinv   = (float*)w; w += 400000;
    int* perm     = (int*)w; w += 400128;                // 100032 ints
    int* bucketCursor = (int*)w; w += NB * 16 * 4;
    int* bucketStart  = (int*)w; w += 1024;
    int* degHist  = (int*)w; w += 1024;
    int* binCursor= (int*)w; w += 1024;
    u16* w1t = (u16*)w; w += 80 * 128 * 2;
    u16* w2t = (u16*)w; w += 48 * 96 * 2;
    int* flag = (int*)w; w += 16;

    probe64<<<1, 256, 0, stream>>>(e, flag);
    init_misc<<<3126, 256, 0, stream>>>(bucketCursor, degHist, (u32*)h1b);
    passA<<<(N_EDGES + PA_EDGES - 1) / PA_EDGES, 256, 0, stream>>>(
        e, flag, bucketCursor, bucketBuf);
    scan196<<<1, 256, 0, stream>>>(bucketCursor, bucketStart, rowStart);
    passB<<<NB, 1024, 0, stream>>>(bucketBuf, bucketCursor, bucketStart,
                                   csrSrc, rowStart, dinv);
    hist_deg<<<98, 1024, 0, stream>>>(rowStart, degHist);
    scan_bins<<<1, 256, 0, stream>>>(degHist, binCursor);
    scatter_perm<<<98, 1024, 0, stream>>>(rowStart, binCursor, perm);
    prep_w<<<16, 256, 0, stream>>>(W1, W2, w1t, w2t);

    gemm1_mfma<<<(N_NODES + 63) / 64, 256, 0, stream>>>(
        x, w1t, dinv, hsC0, hsC1, hsC2);
    agg1_c32<<<3126, 256, 0, stream>>>(
        hsC0, rowStart, csrSrc, perm, dinv, b1, (u32*)h1b, 0);
    agg1_c32<<<3126, 256, 0, stream>>>(
        hsC1, rowStart, csrSrc, perm, dinv, b1, (u32*)h1b, 32);
    agg1_c16<<<1563, 256, 0, stream>>>(
        hsC2, rowStart, csrSrc, perm, dinv, b1, (u32*)h1b);
    gemm2_mfma<<<(N_NODES + 63) / 64, 256, 0, stream>>>(h1b, w2t, dinv, hs2P);
    aggregate2<<<3125, 256, 0, stream>>>(
        (const char*)hs2P, rowStart, csrSrc, perm, dinv, b2, out);
}

// Round 15
// 227.488 us; speedup vs baseline: 1.1360x; 1.1360x over previous
//
#include <hip/hip_runtime.h>

#define N_NODES 100000
#define IN_CH 128
#define HID 75
#define OUT_CH 40
#define N_EDGES 3200000

#define NB 391          // buckets of 256 dst nodes (390*256+160 = 100000)
#define CAP 10000       // per-bucket capacity; mean 8184, ~20 sigma headroom
#define EPT 16          // edges per thread in passA
#define PA_EDGES (EPT * 256)

typedef unsigned short u16;
typedef unsigned int u32;
typedef unsigned char u8;
typedef short short8 __attribute__((ext_vector_type(8)));
typedef float f32x4 __attribute__((ext_vector_type(4)));
typedef float f32x2 __attribute__((ext_vector_type(2)));
typedef u32 u32x2 __attribute__((ext_vector_type(2)));
typedef u32 u32x4 __attribute__((ext_vector_type(4)));
typedef u32x4 u32x4u __attribute__((aligned(4)));   // 4B-aligned dwordx4 load

__device__ __forceinline__ u16 f2bf(float f) {
    u32 b = __float_as_uint(f);
    b += 0x7FFF + ((b >> 16) & 1);   // round-to-nearest-even
    return (u16)(b >> 16);
}

#if __has_builtin(__builtin_amdgcn_cvt_pk_f32_fp8) && __has_builtin(__builtin_amdgcn_cvt_pk_fp8_f32)
#define HW_FP8 1
#else
#define HW_FP8 0
#endif

// ---- fp8 e4m3 decode: 2 values from the low/high word of a u32 -----------
__device__ __forceinline__ float dec1_sw(u32 v) {
    u32 s = (v & 0x80u) << 24;
    u32 em = v & 0x7Fu;
    float mag = (em >= 8u) ? __uint_as_float((em << 20) + (120u << 23))
                           : (float)em * 0.001953125f;   // denormal: m * 2^-9
    return __uint_as_float(s | __float_as_uint(mag));
}
template <int HI>
__device__ __forceinline__ f32x2 dec2(u32 w) {
#if HW_FP8
    return __builtin_amdgcn_cvt_pk_f32_fp8(w, HI);
#else
    f32x2 r;
    r.x = dec1_sw((w >> (HI * 16)) & 0xFFu);
    r.y = dec1_sw((w >> (HI * 16 + 8)) & 0xFFu);
    return r;
#endif
}
// ---- fp8 e4m3 encode (RNE, clamp to +-448) -------------------------------
__device__ __forceinline__ u32 enc1(float f) {
#if HW_FP8
    return __builtin_amdgcn_cvt_pk_fp8_f32(f, f, 0u, false) & 0xFFu;
#else
    float cf = fminf(fmaxf(f, -448.f), 448.f);
    u32 b = __float_as_uint(cf);
    u32 sign = (b >> 24) & 0x80u;
    float af = fabsf(cf);
    if (af < 0.015625f) {                       // denormal range, step 2^-9
        u32 d = (u32)__builtin_rintf(af * 512.f);
        return sign | d;
    }
    u32 e = (b >> 23) & 0xFFu;
    u32 m = b & 0x7FFFFFu;
    u32 m8 = m >> 20;
    u32 rem = m & 0xFFFFFu;
    m8 += (rem > 0x80000u) || (rem == 0x80000u && (m8 & 1u));
    u32 ee = e - 120u;
    if (m8 == 8u) { m8 = 0u; ee += 1u; }
    if (ee > 15u || (ee == 15u && m8 == 7u)) { ee = 15u; m8 = 6u; }  // 448
    return sign | (ee << 3) | m8;
#endif
}

// ---------------- edge-index layout probe (int32 vs int64) ----------------
__global__ void probe64(const int* __restrict__ e, int* __restrict__ flag) {
    __shared__ int nonzero;
    if (threadIdx.x == 0) nonzero = 0;
    __syncthreads();
    int idx = threadIdx.x * 12497;              // < 3.2M
    if (e[2 * idx + 1] != 0) nonzero = 1;       // safe for both layouts
    __syncthreads();
    if (threadIdx.x == 0) *flag = (nonzero == 0) ? 1 : 0;
}

// zero bucket cursors, degree histogram, h1b K-pad (u32 cols 40..47)
__global__ __launch_bounds__(256) void init_misc(int* __restrict__ bucketCursor,
        int* __restrict__ degHist, u32* __restrict__ h1b32) {
    int i = blockIdx.x * 256 + threadIdx.x;
    if (i < NB * 16) bucketCursor[i] = 0;
    if (i < 256) degHist[i] = 0;
    if (i < 800000) {
        int node = i >> 3, q = i & 7;
        h1b32[node * 48 + 40 + q] = 0;
    }
}

// ---------------- pass A: bin edges into 391 dst-range buckets ------------
// LDS-staged: place into block-local bucket runs, then coalesced copy-out.
__global__ __launch_bounds__(256) void passA(const int* __restrict__ e,
        const int* __restrict__ flag, int* __restrict__ bucketCursor,
        unsigned* __restrict__ bucketBuf) {
    __shared__ int cnt[NB], cnt2[NB], lscan[NB], delta2[NB];
    __shared__ int sca[512], scb[512];
    __shared__ u32 stage[PA_EDGES];    // 16 KB
    __shared__ u16 stageB[PA_EDGES];   // 8 KB
    __shared__ int totSh;
    int t = threadIdx.x;
    for (int i = t; i < NB; i += 256) { cnt[i] = 0; cnt2[i] = 0; }
    __syncthreads();
    bool w64 = (*flag != 0);
    int s_[EPT], d_[EPT];
    int eb = blockIdx.x * PA_EDGES + t;
#pragma unroll
    for (int k = 0; k < EPT; ++k) {
        int idx = eb + k * 256;
        int s = 0, d = -1;
        if (idx < N_EDGES) {
            if (w64) { s = e[2 * idx]; d = e[2 * (N_EDGES + idx)]; }
            else     { s = e[idx];     d = e[N_EDGES + idx]; }
            atomicAdd(&cnt[d >> 8], 1);
        }
        s_[k] = s; d_[k] = d;
    }
    __syncthreads();
    // exclusive scan of cnt[0..NB) (padded to 512, 256 threads x 2 lanes)
    sca[t] = (t < NB) ? cnt[t] : 0;
    sca[t + 256] = (t + 256 < NB) ? cnt[t + 256] : 0;
    __syncthreads();
    int* pin = sca; int* pout = scb;
    for (int o = 1; o < 512; o <<= 1) {
        pout[t] = pin[t] + ((t >= o) ? pin[t - o] : 0);
        int i1 = t + 256;
        pout[i1] = pin[i1] + ((i1 >= o) ? pin[i1 - o] : 0);
        __syncthreads();
        int* tmp = pin; pin = pout; pout = tmp;
    }
    for (int i = t; i < NB; i += 256) lscan[i] = pin[i] - cnt[i];
    if (t == 0) totSh = pin[511];
    __syncthreads();
    // reserve global space per bucket (64B-padded cursors)
    for (int i = t; i < NB; i += 256) {
        int c = cnt[i];
        int b0 = (c > 0) ? atomicAdd(&bucketCursor[i * 16], c) : 0;
        delta2[i] = i * CAP + b0 - lscan[i];
    }
    __syncthreads();
    // place into LDS stage (bucket-run order)
#pragma unroll
    for (int k = 0; k < EPT; ++k) {
        int d = d_[k];
        if (d >= 0) {
            int b = d >> 8;
            int off = atomicAdd(&cnt2[b], 1);
            int pl = lscan[b] + off;
            stage[pl] = ((unsigned)(d & 255) << 17) | (unsigned)s_[k];
            stageB[pl] = (u16)b;
        }
    }
    __syncthreads();
    // coalesced copy-out: consecutive i -> mostly consecutive global addrs
    int tot = totSh;
    for (int i = t; i < tot; i += 256) {
        int bb = stageB[i];
        int wpos = delta2[bb] + i;
        if (wpos - bb * CAP < CAP) bucketBuf[wpos] = stage[i];
    }
}

// ---------------- scan of 391 bucket sizes -> bucket starts ---------------
__global__ __launch_bounds__(512) void scan391(const int* __restrict__ bucketCursor,
        int* __restrict__ bucketStart, int* __restrict__ rowStart) {
    __shared__ int a[512], b[512];
    int t = threadIdx.x;
    int v = (t < NB) ? bucketCursor[t * 16] : 0;
    a[t] = v;
    __syncthreads();
    int* pin = a; int* pout = b;
    for (int o = 1; o < 512; o <<= 1) {
        int nv = pin[t] + ((t >= o) ? pin[t - o] : 0);
        pout[t] = nv;
        __syncthreads();
        int* tmp = pin; pin = pout; pout = tmp;
    }
    if (t < NB) bucketStart[t] = pin[t] - v;  // exclusive
    if (t == 0) rowStart[N_NODES] = N_EDGES;
}

// ---------------- pass B: per-bucket CSR fill, LDS-staged coalesced out ---
__global__ __launch_bounds__(1024) void passB(const unsigned* __restrict__ bucketBuf,
        const int* __restrict__ bucketCursor, const int* __restrict__ bucketStart,
        int* __restrict__ csrSrc, int* __restrict__ rowStart, float* __restrict__ dinv) {
    __shared__ int cnt[256];
    __shared__ int sa[256], sb[256];
    __shared__ int stage[CAP];         // 40 KB
    int b = blockIdx.x;
    int t = threadIdx.x;
    int n = min(bucketCursor[b * 16], CAP);
    int start = bucketStart[b];
    if (t < 256) cnt[t] = 0;
    __syncthreads();
    const unsigned* buf = bucketBuf + (size_t)b * CAP;
    for (int i = t; i < n; i += 1024) atomicAdd(&cnt[buf[i] >> 17], 1);
    __syncthreads();
    if (t < 256) sa[t] = cnt[t];
    __syncthreads();
    int* pin = sa; int* pout = sb;
    for (int o = 1; o < 256; o <<= 1) {
        if (t < 256) pout[t] = pin[t] + ((t >= o) ? pin[t - o] : 0);
        __syncthreads();
        int* tmp = pin; pin = pout; pout = tmp;
    }
    int excl = 0;
    if (t < 256) {
        int deg = cnt[t];
        excl = pin[t] - deg;
        int node = b * 256 + t;
        if (node < N_NODES) {
            rowStart[node] = start + excl;
            dinv[node] = rsqrtf((float)deg + 1.0f);  // +1 self-loop
        }
    }
    __syncthreads();
    if (t < 256) cnt[t] = excl;   // LDS cursors
    __syncthreads();
    for (int i = t; i < n; i += 1024) {
        unsigned p = buf[i];
        int pos = atomicAdd(&cnt[p >> 17], 1);
        stage[pos] = (int)(p & 0x1FFFF);
    }
    __syncthreads();
    for (int i = t; i < n; i += 1024) csrSrc[start + i] = stage[i];  // coalesced
}

// ---------------- degree-sorted node permutation (two-level LDS sort) -----
__global__ __launch_bounds__(1024) void hist_deg(const int* __restrict__ rowStart,
        int* __restrict__ degHist) {
    __shared__ int lh[256];
    int t = threadIdx.x;
    if (t < 256) lh[t] = 0;
    __syncthreads();
    int i = blockIdx.x * 1024 + t;
    if (i < N_NODES) {
        int deg = min(rowStart[i + 1] - rowStart[i], 255);
        atomicAdd(&lh[deg], 1);
    }
    __syncthreads();
    if (t < 256 && lh[t] > 0) atomicAdd(&degHist[t], lh[t]);
}
__global__ __launch_bounds__(256) void scan_bins(const int* __restrict__ degHist,
        int* __restrict__ binCursor) {
    __shared__ int a[256], b[256];
    int t = threadIdx.x;
    int v = degHist[t];
    a[t] = v;
    __syncthreads();
    int* pin = a; int* pout = b;
    for (int o = 1; o < 256; o <<= 1) {
        pout[t] = pin[t] + ((t >= o) ? pin[t - o] : 0);
        __syncthreads();
        int* tmp = pin; pin = pout; pout = tmp;
    }
    binCursor[t] = pin[t] - v;   // exclusive
}
__global__ __launch_bounds__(1024) void scatter_perm(const int* __restrict__ rowStart,
        int* __restrict__ binCursor, int* __restrict__ perm) {
    __shared__ int lh[256];
    __shared__ int lbase[256];
    int t = threadIdx.x;
    if (t < 256) lh[t] = 0;
    __syncthreads();
    int i = blockIdx.x * 1024 + t;
    int deg = 0, lo = 0;
    bool valid = (i < N_NODES);
    if (valid) {
        deg = min(rowStart[i + 1] - rowStart[i], 255);
        lo = atomicAdd(&lh[deg], 1);          // local offset (LDS, fast)
    }
    __syncthreads();
    if (t < 256) {
        int c = lh[t];
        lbase[t] = (c > 0) ? atomicAdd(&binCursor[t], c) : 0;
    }
    __syncthreads();
    if (valid) perm[lbase[deg] + lo] = i;
    else if (i < 100032) perm[i] = N_NODES;   // sentinel pad
}

// ---------------- prep: bf16 transposed weights ---------------------------
__global__ __launch_bounds__(256) void prep_w(const float* __restrict__ W1,
        const float* __restrict__ W2, u16* __restrict__ w1t, u16* __restrict__ w2t) {
    int g = blockIdx.x * 256 + threadIdx.x;
    int stride = gridDim.x * 256;
    for (int i = g; i < 80 * 128; i += stride) {
        int c = i >> 7, k = i & 127;
        w1t[i] = (c < HID) ? f2bf(W1[k * HID + c]) : (u16)0;
    }
    for (int i = g; i < 48 * 96; i += stride) {
        int c = i / 96, k = i - c * 96;
        w2t[i] = (c < OUT_CH && k < HID) ? f2bf(W2[k * OUT_CH + c]) : (u16)0;
    }
}

// ---------------- GEMM1 via MFMA -> fp8 tables (SCALE=8 folded in) --------
// hsA8[node][64 u8] (feats 0..63, 64B rows), hsB8[node][16 u8] (feats 64..79)
__global__ __launch_bounds__(256) void gemm1_mfma(const float* __restrict__ x,
        const u16* __restrict__ w1t, const float* __restrict__ dinv,
        u8* __restrict__ hsA8, u8* __restrict__ hsB8) {
    __shared__ u16 Wl[80 * 136];   // pad 128->136 elems: bank-spread rows
    int t = threadIdx.x;
    {
        const u32* ws = (const u32*)w1t;
        u32* wd = (u32*)Wl;
        for (int i = t; i < 80 * 64; i += 256) {
            int r = i >> 6, c = i & 63;
            wd[r * 68 + c] = ws[i];
        }
    }
    __syncthreads();
    int wid = t >> 6, lane = t & 63;
    int bl = lane & 15, kh = lane >> 4;
    int row0 = blockIdx.x * 64 + wid * 16;
    short8 bf[5][4];
#pragma unroll
    for (int ct = 0; ct < 5; ++ct)
#pragma unroll
        for (int ks = 0; ks < 4; ++ks)
            bf[ct][ks] = *(const short8*)&Wl[(ct * 16 + bl) * 136 + ks * 32 + kh * 8];
    f32x4 zero = {0.f, 0.f, 0.f, 0.f};
    f32x4 acc[5];
#pragma unroll
    for (int ct = 0; ct < 5; ++ct) acc[ct] = zero;
    int arow = row0 + bl;
    bool av = (arow < N_NODES);
    const float* xr = x + (size_t)arow * IN_CH + kh * 8;
#pragma unroll
    for (int ks = 0; ks < 4; ++ks) {
        short8 af = {0, 0, 0, 0, 0, 0, 0, 0};
        if (av) {
            float4 lo = *(const float4*)(xr + ks * 32);
            float4 hi = *(const float4*)(xr + ks * 32 + 4);
            af[0] = (short)f2bf(lo.x); af[1] = (short)f2bf(lo.y);
            af[2] = (short)f2bf(lo.z); af[3] = (short)f2bf(lo.w);
            af[4] = (short)f2bf(hi.x); af[5] = (short)f2bf(hi.y);
            af[6] = (short)f2bf(hi.z); af[7] = (short)f2bf(hi.w);
        }
#pragma unroll
        for (int ct = 0; ct < 5; ++ct)
            acc[ct] = __builtin_amdgcn_mfma_f32_16x16x32_bf16(af, bf[ct][ks], acc[ct], 0, 0, 0);
    }
    // C/D: col = lane&15, row = (lane>>4)*4 + reg  [HW-verified]
    int orow = row0 + kh * 4;
    float dn[4];
#pragma unroll
    for (int i = 0; i < 4; ++i)
        dn[i] = (orow + i < N_NODES) ? dinv[orow + i] * 8.f : 0.f;   // SCALE=8
#pragma unroll
    for (int ct = 0; ct < 5; ++ct) {
        int col = ct * 16 + bl;
#pragma unroll
        for (int i = 0; i < 4; ++i) {
            int r = orow + i;
            if (r < N_NODES) {
                u8 q8 = (u8)enc1(acc[ct][i] * dn[i]);
                if (ct < 4) hsA8[(size_t)r * 64 + col] = q8;
                else        hsB8[(size_t)r * 16 + (col - 64)] = q8;
            }
        }
    }
}

// ---------------- GEMM2 via MFMA -> single padded fp8 table (SCALE=8) -----
// hs2P[node][64 u8]: feats 0..39 in bytes 0..39, bytes 40..63 unused pad
__global__ __launch_bounds__(256) void gemm2_mfma(const u16* __restrict__ h1b,
        const u16* __restrict__ w2t, const float* __restrict__ dinv,
        u8* __restrict__ hs2P) {
    __shared__ u16 Wl[48 * 104];   // pad 96->104
    int t = threadIdx.x;
    {
        const u32* ws = (const u32*)w2t;
        u32* wd = (u32*)Wl;
        for (int i = t; i < 48 * 48; i += 256) {
            int r = i / 48, c = i - r * 48;
            wd[r * 52 + c] = ws[i];
        }
    }
    __syncthreads();
    int wid = t >> 6, lane = t & 63;
    int bl = lane & 15, kh = lane >> 4;
    int row0 = blockIdx.x * 64 + wid * 16;
    short8 bf[3][3];
#pragma unroll
    for (int ct = 0; ct < 3; ++ct)
#pragma unroll
        for (int ks = 0; ks < 3; ++ks)
            bf[ct][ks] = *(const short8*)&Wl[(ct * 16 + bl) * 104 + ks * 32 + kh * 8];
    f32x4 zero = {0.f, 0.f, 0.f, 0.f};
    f32x4 acc[3];
#pragma unroll
    for (int ct = 0; ct < 3; ++ct) acc[ct] = zero;
    int arow = row0 + bl;
    bool av = (arow < N_NODES);
    const u16* hr = h1b + (size_t)arow * 96 + kh * 8;
#pragma unroll
    for (int ks = 0; ks < 3; ++ks) {
        short8 af = {0, 0, 0, 0, 0, 0, 0, 0};
        if (av) af = *(const short8*)(hr + ks * 32);
#pragma unroll
        for (int ct = 0; ct < 3; ++ct)
            acc[ct] = __builtin_amdgcn_mfma_f32_16x16x32_bf16(af, bf[ct][ks], acc[ct], 0, 0, 0);
    }
    int orow = row0 + kh * 4;
    float dn[4];
#pragma unroll
    for (int i = 0; i < 4; ++i)
        dn[i] = (orow + i < N_NODES) ? dinv[orow + i] * 8.f : 0.f;   // SCALE=8
#pragma unroll
    for (int ct = 0; ct < 3; ++ct) {
        int col = ct * 16 + bl;
#pragma unroll
        for (int i = 0; i < 4; ++i) {
            int r = orow + i;
            if (r < N_NODES && (ct < 2 || bl < 8)) {   // cols 0..39 only
                u8 q8 = (u8)enc1(acc[ct][i] * dn[i]);
                hs2P[(size_t)r * 64 + col] = q8;
            }
        }
    }
}

// ---------------- aggregation layer 1: group-per-node, no cross-lane ------
// 12 groups x 5 lanes per wave; each group owns one (degree-sorted) node and
// loops its own edges. Lane ll<4: 16B of 64B hsA8 row; ll==4: hsB8 row.
__global__ __launch_bounds__(256) void aggregate1(
        const char* __restrict__ tab, int delta1,
        const int* __restrict__ rowStart, const int* __restrict__ csrSrc,
        const int* __restrict__ perm, const float* __restrict__ dinv,
        const float* __restrict__ bias, u32* __restrict__ out) {
    int wid = threadIdx.x >> 6, lane = threadIdx.x & 63;
    int g = lane / 5;                  // 0..12 (lanes 60..63 -> 12, inactive)
    int ll = lane - 5 * g;
    bool glane = (g < 12);
    int slot = (blockIdx.x * 4 + wid) * 12 + (glane ? g : 0);   // < 100032
    int node = perm[slot];
    bool valid = glane && (node < N_NODES);
    int vnode = valid ? node : 0;
    int rs = rowStart[vnode];
    int end = valid ? rowStart[vnode + 1] : rs;
    bool isB = (ll == 4);
    u32 loff = isB ? (u32)delta1 : (u32)ll * 16;
    int sh = isB ? 4 : 6;              // row stride 16B / 64B
    f32x2 acc[8];
#pragma unroll
    for (int k = 0; k < 8; ++k) { acc[k].x = 0.f; acc[k].y = 0.f; }
    if (valid) {                       // self-loop
        u32x4 v = *(const u32x4*)(tab + (((u32)vnode << sh) + loff));
        acc[0] += dec2<0>(v.x); acc[1] += dec2<1>(v.x);
        acc[2] += dec2<0>(v.y); acc[3] += dec2<1>(v.y);
        acc[4] += dec2<0>(v.z); acc[5] += dec2<1>(v.z);
        acc[6] += dec2<0>(v.w); acc[7] += dec2<1>(v.w);
    }
    int j = rs;
    for (; j + 4 <= end; j += 4) {
        u32x4 i4 = *(const u32x4u*)(csrSrc + j);   // same addr across group
#pragma unroll
        for (int q = 0; q < 4; ++q) {
            u32x4 v = *(const u32x4*)(tab + ((i4[q] << sh) + loff));
            acc[0] += dec2<0>(v.x); acc[1] += dec2<1>(v.x);
            acc[2] += dec2<0>(v.y); acc[3] += dec2<1>(v.y);
            acc[4] += dec2<0>(v.z); acc[5] += dec2<1>(v.z);
            acc[6] += dec2<0>(v.w); acc[7] += dec2<1>(v.w);
        }
    }
    for (; j < end; ++j) {
        u32 idx = (u32)csrSrc[j];
        u32x4 v = *(const u32x4*)(tab + ((idx << sh) + loff));
        acc[0] += dec2<0>(v.x); acc[1] += dec2<1>(v.x);
        acc[2] += dec2<0>(v.y); acc[3] += dec2<1>(v.y);
        acc[4] += dec2<0>(v.z); acc[5] += dec2<1>(v.z);
        acc[6] += dec2<0>(v.w); acc[7] += dec2<1>(v.w);
    }
    if (valid) {
        float dns = dinv[vnode] * 0.125f;   // undo SCALE=8
        u32x4 o0, o1;
#pragma unroll
        for (int k = 0; k < 8; ++k) {
            int f0 = 16 * ll + 2 * k;
            float rlo = (f0 < HID) ? fmaxf(fmaf(dns, acc[k].x, bias[f0]), 0.f) : 0.f;
            float rhi = (f0 + 1 < HID) ? fmaxf(fmaf(dns, acc[k].y, bias[f0 + 1]), 0.f) : 0.f;
            u32 wd = ((u32)f2bf(rhi) << 16) | (u32)f2bf(rlo);
            if (k < 4) o0[k] = wd; else o1[k - 4] = wd;
        }
        *(u32x4*)(out + (size_t)vnode * 48 + 8 * ll) = o0;
        *(u32x4*)(out + (size_t)vnode * 48 + 8 * ll + 4) = o1;
    }
}

// ---------------- aggregation layer 2: 8x8 groups + log_softmax -----------
__global__ __launch_bounds__(256) void aggregate2(
        const char* __restrict__ tab,
        const int* __restrict__ rowStart, const int* __restrict__ csrSrc,
        const int* __restrict__ perm, const float* __restrict__ dinv,
        const float* __restrict__ bias, float* __restrict__ out) {
    int wid = threadIdx.x >> 6, lane = threadIdx.x & 63;
    int g = lane >> 3, ll = lane & 7;
    int slot = (blockIdx.x * 4 + wid) * 8 + g;      // grid exact: < 100000
    int node = perm[slot];
    int rs = rowStart[node];
    int end = rowStart[node + 1];
    u32 loff = (u32)ll * 8;
    f32x2 a0 = {0.f, 0.f}, a1 = {0.f, 0.f}, a2 = {0.f, 0.f}, a3 = {0.f, 0.f};
    {                                   // self-loop
        u32x2 v = *(const u32x2*)(tab + (((u32)node << 6) + loff));
        a0 += dec2<0>(v.x); a1 += dec2<1>(v.x);
        a2 += dec2<0>(v.y); a3 += dec2<1>(v.y);
    }
    int j = rs;
    for (; j + 4 <= end; j += 4) {
        u32x4 i4 = *(const u32x4u*)(csrSrc + j);
#pragma unroll
        for (int q = 0; q < 4; ++q) {
            u32x2 v = *(const u32x2*)(tab + ((i4[q] << 6) + loff));
            a0 += dec2<0>(v.x); a1 += dec2<1>(v.x);
            a2 += dec2<0>(v.y); a3 += dec2<1>(v.y);
        }
    }
    for (; j < end; ++j) {
        u32 idx = (u32)csrSrc[j];
        u32x2 v = *(const u32x2*)(tab + ((idx << 6) + loff));
        a0 += dec2<0>(v.x); a1 += dec2<1>(v.x);
        a2 += dec2<0>(v.y); a3 += dec2<1>(v.y);
    }
    float tt[8] = {a0.x, a0.y, a1.x, a1.y, a2.x, a2.y, a3.x, a3.y};
    bool act5 = (ll < 5);
    float vk[8];
    float m = -3.4e38f;
    if (act5) {
        float dns = dinv[node] * 0.125f;   // undo SCALE=8
#pragma unroll
        for (int k = 0; k < 8; ++k) {
            vk[k] = fmaf(dns, tt[k], bias[8 * ll + k]);
            m = fmaxf(m, vk[k]);
        }
    }
#pragma unroll
    for (int o = 1; o < 8; o <<= 1) m = fmaxf(m, __shfl_xor(m, o));
    float e = 0.f;
    if (act5) {
#pragma unroll
        for (int k = 0; k < 8; ++k) e += expf(vk[k] - m);
    }
#pragma unroll
    for (int o = 1; o < 8; o <<= 1) e += __shfl_xor(e, o);
    float lse = logf(e);
    if (act5) {
        float4 r0 = make_float4(vk[0] - m - lse, vk[1] - m - lse,
                                vk[2] - m - lse, vk[3] - m - lse);
        float4 r1 = make_float4(vk[4] - m - lse, vk[5] - m - lse,
                                vk[6] - m - lse, vk[7] - m - lse);
        *(float4*)(out + (size_t)node * OUT_CH + 8 * ll) = r0;
        *(float4*)(out + (size_t)node * OUT_CH + 8 * ll + 4) = r1;
    }
}

extern "C" void kernel_launch(void* const* d_in, const int* in_sizes, int n_in,
                              void* d_out, int out_size, void* d_ws, size_t ws_size,
                              hipStream_t stream) {
    const float* x  = (const float*)d_in[0];
    const int*   e  = (const int*)d_in[1];
    const float* W1 = (const float*)d_in[2];
    const float* b1 = (const float*)d_in[3];
    const float* W2 = (const float*)d_in[4];
    const float* b2 = (const float*)d_in[5];
    float* out = (float*)d_out;

    // workspace carve (all sizes multiples of 16 B); total ~57 MB
    char* w = (char*)d_ws;
    u8* hsA8 = (u8*)w;                                   // 6.40 MB  (aliases bucketBuf)
    u8* hsB8 = (u8*)(w + 6402048);                       // 1.60 MB  (aliases bucketBuf)
    unsigned* bucketBuf = (unsigned*)w;                  // 391*10000*4 = 15.64 MB
    w += 15680000;
    u16* h1b  = (u16*)w; w += (size_t)100032 * 96 * 2;   // 19.2 MB
    int* csrSrc = (int*)w; w += (size_t)N_EDGES * 4;     // 12.8 MB
    u8* hs2P = (u8*)w; w += (size_t)100032 * 64;         // 6.40 MB
    int* rowStart = (int*)w; w += 400016;
    float* dinv   = (float*)w; w += 400000;
    int* perm     = (int*)w; w += 400128;                // 100032 ints
    int* bucketCursor = (int*)w; w += NB * 16 * 4;
    int* bucketStart  = (int*)w; w += 2048;
    int* degHist  = (int*)w; w += 1024;
    int* binCursor= (int*)w; w += 1024;
    u16* w1t = (u16*)w; w += 80 * 128 * 2;
    u16* w2t = (u16*)w; w += 48 * 96 * 2;
    int* flag = (int*)w; w += 16;

    int delta1 = (int)((char*)hsB8 - (char*)hsA8);       // 6,402,048

    probe64<<<1, 256, 0, stream>>>(e, flag);
    init_misc<<<3126, 256, 0, stream>>>(bucketCursor, degHist, (u32*)h1b);
    passA<<<(N_EDGES + PA_EDGES - 1) / PA_EDGES, 256, 0, stream>>>(
        e, flag, bucketCursor, bucketBuf);
    scan391<<<1, 512, 0, stream>>>(bucketCursor, bucketStart, rowStart);
    passB<<<NB, 1024, 0, stream>>>(bucketBuf, bucketCursor, bucketStart,
                                   csrSrc, rowStart, dinv);
    hist_deg<<<98, 1024, 0, stream>>>(rowStart, degHist);
    scan_bins<<<1, 256, 0, stream>>>(degHist, binCursor);
    scatter_perm<<<98, 1024, 0, stream>>>(rowStart, binCursor, perm);
    prep_w<<<16, 256, 0, stream>>>(W1, W2, w1t, w2t);

    gemm1_mfma<<<(N_NODES + 63) / 64, 256, 0, stream>>>(x, w1t, dinv, hsA8, hsB8);
    aggregate1<<<2084, 256, 0, stream>>>(
        (const char*)hsA8, delta1, rowStart, csrSrc, perm, dinv, b1, (u32*)h1b);
    gemm2_mfma<<<(N_NODES + 63) / 64, 256, 0, stream>>>(h1b, w2t, dinv, hs2P);
    aggregate2<<<3125, 256, 0, stream>>>(
        (const char*)hs2P, rowStart, csrSrc, perm, dinv, b2, out);
}